// Round 1
// baseline (1333.933 us; speedup 1.0000x reference)
//
#include <hip/hip_runtime.h>
#include <hip/hip_bf16.h>

// Problem constants
#define NEXP 8
#define KIN 2048
#define NOUT 2048
#define NTOK 32768

// GEMM tile
#define BM 128
#define BN 128
#define BK 32

typedef unsigned int u32;
typedef unsigned short u16;
typedef __bf16 bf16x8 __attribute__((ext_vector_type(8)));
typedef float f32x4 __attribute__((ext_vector_type(4)));

// ctrl layout (ints): [0..7]=counts, [8..15]=fill, [16..24]=tokenStart(9), [25..33]=tileStart(9)
#define C_COUNT 0
#define C_FILL 8
#define C_TOKST 16
#define C_TILST 25

__device__ __forceinline__ u16 f2bf(float f) {
    u32 u = __float_as_uint(f);
    u += 0x7FFFu + ((u >> 16) & 1u);   // round-to-nearest-even; inputs are finite
    return (u16)(u >> 16);
}

__device__ __forceinline__ void load_lds16(const void* g, void* l) {
    __builtin_amdgcn_global_load_lds(
        (const __attribute__((address_space(1))) u32*)g,
        (__attribute__((address_space(3))) u32*)l, 16, 0, 0);
}

__global__ void hist_k(const int* __restrict__ assign, int* __restrict__ ctrl) {
    int t = blockIdx.x * 256 + threadIdx.x;
    if (t < NTOK) atomicAdd(&ctrl[C_COUNT + assign[t]], 1);
}

__global__ void prefix_k(int* __restrict__ ctrl) {
    if (threadIdx.x == 0) {
        int ts = 0, tls = 0;
        for (int e = 0; e < NEXP; e++) {
            ctrl[C_TOKST + e] = ts;
            ctrl[C_TILST + e] = tls;
            int c = ctrl[C_COUNT + e];
            ts += c;
            tls += (c + BM - 1) / BM;
        }
        ctrl[C_TOKST + NEXP] = ts;
        ctrl[C_TILST + NEXP] = tls;
    }
}

__global__ void scatter_k(const int* __restrict__ assign, int* __restrict__ ctrl,
                          int* __restrict__ list) {
    int t = blockIdx.x * 256 + threadIdx.x;
    if (t < NTOK) {
        int e = assign[t];
        int p = ctrl[C_TOKST + e] + atomicAdd(&ctrl[C_FILL + e], 1);
        list[p] = t;
    }
}

// Gather rows in expert-sorted order and convert fp32 -> bf16 (vec8 per thread).
__global__ void gatherA_k(const float* __restrict__ A, const int* __restrict__ list,
                          u16* __restrict__ sA) {
    int i = blockIdx.x * 256 + threadIdx.x;      // vec8 id, total NTOK*KIN/8
    int row = i >> 8;                            // KIN/8 == 256 vec8 per row
    int c8 = (i & 255) << 3;
    int tok = list[row];
    const float4* src = (const float4*)(A + (size_t)tok * KIN + c8);
    float4 f0 = src[0], f1 = src[1];
    uint4 o;
    o.x = (u32)f2bf(f0.x) | ((u32)f2bf(f0.y) << 16);
    o.y = (u32)f2bf(f0.z) | ((u32)f2bf(f0.w) << 16);
    o.z = (u32)f2bf(f1.x) | ((u32)f2bf(f1.y) << 16);
    o.w = (u32)f2bf(f1.z) | ((u32)f2bf(f1.w) << 16);
    *(uint4*)(sA + (size_t)row * KIN + c8) = o;
}

__global__ void convW_k(const float* __restrict__ W, u16* __restrict__ Wb) {
    int i = blockIdx.x * 256 + threadIdx.x;      // vec8 id, total NEXP*NOUT*KIN/8
    size_t off = (size_t)i << 3;
    const float4* src = (const float4*)(W + off);
    float4 f0 = src[0], f1 = src[1];
    uint4 o;
    o.x = (u32)f2bf(f0.x) | ((u32)f2bf(f0.y) << 16);
    o.y = (u32)f2bf(f0.z) | ((u32)f2bf(f0.w) << 16);
    o.z = (u32)f2bf(f1.x) | ((u32)f2bf(f1.y) << 16);
    o.w = (u32)f2bf(f1.z) | ((u32)f2bf(f1.w) << 16);
    *(uint4*)(Wb + off) = o;
}

// Grouped GEMM: out[list[p]][n] = sum_k sA[p][k] * Wb[e][n][k]
// grid: (16 N-tiles, 263 M-tile slots), block 256 (4 waves, 2x2 over 64x64 quadrants)
__global__ __launch_bounds__(256) void gemm_k(const u16* __restrict__ sA,
                                              const u16* __restrict__ Wb,
                                              const int* __restrict__ list,
                                              const int* __restrict__ ctrl,
                                              float* __restrict__ out) {
    __shared__ u16 As[BM * BK];   // 8 KiB
    __shared__ u16 Bs[BN * BK];   // 8 KiB

    int mt = blockIdx.y;
    if (mt >= ctrl[C_TILST + NEXP]) return;
    int e = 0;
    while (ctrl[C_TILST + e + 1] <= mt) e++;     // tileStart[e] <= mt < tileStart[e+1]

    int tokStart = ctrl[C_TOKST + e];
    int rowEnd = ctrl[C_TOKST + e + 1];          // == tokStart + count[e]
    int rowBase = tokStart + (mt - ctrl[C_TILST + e]) * BM;  // sorted-space row of tile
    int nBase = blockIdx.x * BN;

    int tid = threadIdx.x;
    // Staging: instr i in {0,1}: row = i*64 + tid/4, col8 = (tid%4)*8
    const u16* ga = sA + (size_t)(rowBase + (tid >> 2)) * KIN + ((tid & 3) << 3);
    const u16* gb = Wb + ((size_t)e * NOUT + nBase + (tid >> 2)) * KIN + ((tid & 3) << 3);
    char* lA = (char*)As + tid * 16;
    char* lB = (char*)Bs + tid * 16;

    int wave = tid >> 6, lane = tid & 63;
    int wm = (wave >> 1) * 64, wn = (wave & 1) * 64;
    int lm = lane & 15, kg = lane >> 4;
    const u16* Ard = As + (wm + lm) * BK + kg * 8;
    const u16* Brd = Bs + (wn + lm) * BK + kg * 8;

    f32x4 acc[4][4];
#pragma unroll
    for (int i = 0; i < 4; i++)
#pragma unroll
        for (int j = 0; j < 4; j++) acc[i][j] = (f32x4){0.f, 0.f, 0.f, 0.f};

    for (int kt = 0; kt < KIN; kt += BK) {
        __syncthreads();                          // all waves done reading prev tiles
        load_lds16(ga + kt, lA);
        load_lds16(ga + (size_t)64 * KIN + kt, lA + 4096);
        load_lds16(gb + kt, lB);
        load_lds16(gb + (size_t)64 * KIN + kt, lB + 4096);
        __syncthreads();                          // staging drained (vmcnt(0) before barrier)

        bf16x8 fa[4], fb[4];
#pragma unroll
        for (int i = 0; i < 4; i++) fa[i] = *(const bf16x8*)(Ard + i * 16 * BK);
#pragma unroll
        for (int j = 0; j < 4; j++) fb[j] = *(const bf16x8*)(Brd + j * 16 * BK);
#pragma unroll
        for (int i = 0; i < 4; i++)
#pragma unroll
            for (int j = 0; j < 4; j++)
                acc[i][j] = __builtin_amdgcn_mfma_f32_16x16x32_bf16(fa[i], fb[j], acc[i][j], 0, 0, 0);
    }

    // Epilogue: C/D layout col=lane&15, row=(lane>>4)*4+reg. Scatter rows via list.
#pragma unroll
    for (int i = 0; i < 4; i++) {
        int r0 = wm + i * 16 + kg * 4;
#pragma unroll
        for (int rr = 0; rr < 4; rr++) {
            int srow = rowBase + r0 + rr;
            if (srow < rowEnd) {
                int tok = list[srow];
                float* orow = out + (size_t)tok * NOUT + nBase + wn + lm;
#pragma unroll
                for (int j = 0; j < 4; j++) orow[j * 16] = acc[i][j][rr];
            }
        }
    }
}

// Correct-but-slow fp32 fallback if ws_size is insufficient.
__global__ void fallback_k(const float* __restrict__ A, const int* __restrict__ assign,
                           const float* __restrict__ W, float* __restrict__ out) {
    long idx = (long)blockIdx.x * 256 + threadIdx.x;  // NTOK*NOUT
    int t = (int)(idx >> 11);
    int n = (int)(idx & (NOUT - 1));
    int e = assign[t];
    const float4* a = (const float4*)(A + (size_t)t * KIN);
    const float4* w = (const float4*)(W + ((size_t)e * NOUT + n) * KIN);
    float s = 0.f;
    for (int k = 0; k < KIN / 4; k++) {
        float4 x = a[k], y = w[k];
        s += x.x * y.x + x.y * y.y + x.z * y.z + x.w * y.w;
    }
    out[idx] = s;
}

extern "C" void kernel_launch(void* const* d_in, const int* in_sizes, int n_in,
                              void* d_out, int out_size, void* d_ws, size_t ws_size,
                              hipStream_t stream) {
    const float* A = (const float*)d_in[0];
    const int* assign = (const int*)d_in[1];
    const float* W = (const float*)d_in[2];
    float* out = (float*)d_out;

    const size_t sA_bytes = (size_t)(NTOK + BM) * KIN * 2;        // padded sorted bf16 A
    const size_t W_bytes = (size_t)NEXP * NOUT * KIN * 2;         // bf16 weights
    const size_t list_bytes = (size_t)NTOK * 4;
    const size_t need = sA_bytes + W_bytes + list_bytes + 1024;

    if (ws_size < need) {
        fallback_k<<<(NTOK * (long)NOUT) / 256, 256, 0, stream>>>(A, assign, W, out);
        return;
    }

    u16* sA = (u16*)d_ws;
    u16* Wb = (u16*)((char*)d_ws + sA_bytes);
    int* list = (int*)((char*)d_ws + sA_bytes + W_bytes);
    int* ctrl = (int*)((char*)d_ws + sA_bytes + W_bytes + list_bytes);

    hipMemsetAsync(ctrl, 0, 256, stream);
    hist_k<<<NTOK / 256, 256, 0, stream>>>(assign, ctrl);
    prefix_k<<<1, 64, 0, stream>>>(ctrl);
    scatter_k<<<NTOK / 256, 256, 0, stream>>>(assign, ctrl, list);
    gatherA_k<<<(NTOK * (KIN / 8)) / 256, 256, 0, stream>>>(A, list, sA);
    convW_k<<<(NEXP * NOUT * (KIN / 8)) / 256, 256, 0, stream>>>(W, Wb);
    dim3 grid(NOUT / BN, NTOK / BM + NEXP - 1);  // 16 x 263 (worst-case tile slots)
    gemm_k<<<grid, 256, 0, stream>>>(sA, Wb, list, ctrl, out);
}

// Round 2
// 875.196 us; speedup vs baseline: 1.5242x; 1.5242x over previous
//
#include <hip/hip_runtime.h>
#include <hip/hip_bf16.h>

// Problem constants
#define NEXP 8
#define KIN 2048
#define NOUT 2048
#define NTOK 32768

// GEMM tile
#define BM 128
#define BN 128
#define BK 32

#define NBLK (NTOK / 256)              // 128 token blocks for rank/scatter
#define MAXTILE (NTOK / BM + NEXP - 1) // 263 worst-case M-tiles

typedef unsigned int u32;
typedef unsigned short u16;
typedef __bf16 bf16x8 __attribute__((ext_vector_type(8)));
typedef float f32x4 __attribute__((ext_vector_type(4)));

__device__ __forceinline__ u16 f2bf(float f) {
    u32 u = __float_as_uint(f);
    u += 0x7FFFu + ((u >> 16) & 1u);   // round-to-nearest-even; inputs are finite
    return (u16)(u >> 16);
}

__device__ __forceinline__ void load_lds16(const void* g, void* l) {
    __builtin_amdgcn_global_load_lds(
        (const __attribute__((address_space(1))) u32*)g,
        (__attribute__((address_space(3))) u32*)l, 16, 0, 0);
}

// Pass 1: per-block LDS histogram + per-token local rank. 8 global atomics/block
// (1024 total) instead of 32768 same-cacheline atomics.
__global__ void rank_k(const int* __restrict__ assign, int* __restrict__ counts,
                       int* __restrict__ rank, int* __restrict__ blockBase) {
    __shared__ int lc[NEXP];
    int t = blockIdx.x * 256 + threadIdx.x;
    if (threadIdx.x < NEXP) lc[threadIdx.x] = 0;
    __syncthreads();
    int e = assign[t];
    rank[t] = atomicAdd(&lc[e], 1);    // LDS atomic: unique local rank
    __syncthreads();
    if (threadIdx.x < NEXP)
        blockBase[blockIdx.x * NEXP + threadIdx.x] =
            atomicAdd(&counts[threadIdx.x], lc[threadIdx.x]);
}

// Pass 2: serial prefix + tile table. ctrl: counts[0..7], tokStart[8..16].
__global__ void prefix_k(int* __restrict__ ctrl, int4* __restrict__ tileTable) {
    if (threadIdx.x == 0) {
        int ts = 0, tile = 0;
        for (int e = 0; e < NEXP; e++) {
            ctrl[8 + e] = ts;
            int c = ctrl[e];
            int ntile = (c + BM - 1) / BM;
            for (int i = 0; i < ntile; i++)
                tileTable[tile++] = make_int4(ts + i * BM, ts + c, e, 0);
            ts += c;
        }
        ctrl[8 + NEXP] = ts;
        for (; tile < MAXTILE; tile++) tileTable[tile] = make_int4(0, 0, 0, 0);
    }
}

// Pass 3: atomic-free scatter using precomputed ranks + block bases.
__global__ void scatter_k(const int* __restrict__ assign, const int* __restrict__ ctrl,
                          const int* __restrict__ rank, const int* __restrict__ blockBase,
                          int* __restrict__ list) {
    __shared__ int base[NEXP];
    int t = blockIdx.x * 256 + threadIdx.x;
    if (threadIdx.x < NEXP)
        base[threadIdx.x] = ctrl[8 + threadIdx.x] +
                            blockBase[blockIdx.x * NEXP + threadIdx.x];
    __syncthreads();
    list[base[assign[t]] + rank[t]] = t;
}

// Streaming fp32 -> bf16 (vec8 per thread). Used for both A and W.
__global__ void conv_k(const float* __restrict__ src, u16* __restrict__ dst) {
    size_t i = ((size_t)blockIdx.x * 256 + threadIdx.x) << 3;
    const float4* s = (const float4*)(src + i);
    float4 f0 = s[0], f1 = s[1];
    uint4 o;
    o.x = (u32)f2bf(f0.x) | ((u32)f2bf(f0.y) << 16);
    o.y = (u32)f2bf(f0.z) | ((u32)f2bf(f0.w) << 16);
    o.z = (u32)f2bf(f1.x) | ((u32)f2bf(f1.y) << 16);
    o.w = (u32)f2bf(f1.z) | ((u32)f2bf(f1.w) << 16);
    *(uint4*)(dst + i) = o;
}

// Grouped GEMM with indirect A staging (rows via token list, no pre-gather) and
// bank-conflict-free chunk swizzle: lane fetches global chunk (slot + row/2)&3,
// reader inverts with slot = (kg - (lm>>1))&3 -> each 16-lane ds_read group
// spreads over all 8 bank-quads (2-way only, free per m136).
__global__ __launch_bounds__(256, 4) void gemm_k(const u16* __restrict__ Ab,
                                                 const u16* __restrict__ Wb,
                                                 const int* __restrict__ list,
                                                 const int4* __restrict__ tileTable,
                                                 float* __restrict__ out) {
    __shared__ u16 As[BM * BK];   // 8 KiB
    __shared__ u16 Bs[BN * BK];   // 8 KiB
    __shared__ int listLds[BM];

    int4 tt = tileTable[blockIdx.y];
    int rowBase = tt.x, rowEnd = tt.y, e = tt.z;
    if (rowEnd <= rowBase) return;            // unused tile slot
    int nBase = blockIdx.x * BN;
    int tid = threadIdx.x;

    if (tid < BM) {
        int r = rowBase + tid;
        listLds[tid] = list[min(r, rowEnd - 1)];  // clamp: dup last row for tail
    }
    __syncthreads();

    int sr = tid >> 2;                        // staging row within 64-row group
    int sc = tid & 3;                         // LDS 16B slot
    int ca = (sc + (sr >> 1)) & 3;            // swizzled global chunk (same for sr+64)
    int tok0 = listLds[sr], tok1 = listLds[sr + 64];
    const u16* ga0 = Ab + (size_t)tok0 * KIN + ca * 8;
    const u16* ga1 = Ab + (size_t)tok1 * KIN + ca * 8;
    const u16* gb  = Wb + ((size_t)e * NOUT + nBase + sr) * KIN + ca * 8;
    char* lA = (char*)As + tid * 16;
    char* lB = (char*)Bs + tid * 16;

    int wave = tid >> 6, lane = tid & 63;
    int wm = (wave >> 1) * 64, wn = (wave & 1) * 64;
    int lm = lane & 15, kg = lane >> 4;
    int sl = (kg - (lm >> 1)) & 3;            // inverse swizzle slot
    const u16* Ard = As + (wm + lm) * BK + sl * 8;
    const u16* Brd = Bs + (wn + lm) * BK + sl * 8;

    f32x4 acc[4][4];
#pragma unroll
    for (int i = 0; i < 4; i++)
#pragma unroll
        for (int j = 0; j < 4; j++) acc[i][j] = (f32x4){0.f, 0.f, 0.f, 0.f};

    for (int kt = 0; kt < KIN; kt += BK) {
        __syncthreads();
        load_lds16(ga0 + kt, lA);
        load_lds16(ga1 + kt, lA + 4096);
        load_lds16(gb + kt, lB);
        load_lds16(gb + (size_t)64 * KIN + kt, lB + 4096);
        __syncthreads();

        bf16x8 fa[4], fb[4];
#pragma unroll
        for (int i = 0; i < 4; i++) fa[i] = *(const bf16x8*)(Ard + i * 16 * BK);
#pragma unroll
        for (int j = 0; j < 4; j++) fb[j] = *(const bf16x8*)(Brd + j * 16 * BK);
#pragma unroll
        for (int i = 0; i < 4; i++)
#pragma unroll
            for (int j = 0; j < 4; j++)
                acc[i][j] = __builtin_amdgcn_mfma_f32_16x16x32_bf16(fa[i], fb[j], acc[i][j], 0, 0, 0);
    }

    // Epilogue: C/D layout col=lane&15, row=(lane>>4)*4+reg. Scatter via listLds.
#pragma unroll
    for (int i = 0; i < 4; i++) {
        int r0 = wm + i * 16 + kg * 4;
#pragma unroll
        for (int rr = 0; rr < 4; rr++) {
            int rl = r0 + rr;
            if (rowBase + rl < rowEnd) {
                int tok = listLds[rl];
                float* orow = out + (size_t)tok * NOUT + nBase + wn + lm;
#pragma unroll
                for (int j = 0; j < 4; j++) orow[j * 16] = acc[i][j][rr];
            }
        }
    }
}

// Correct-but-slow fp32 fallback if ws_size is insufficient.
__global__ void fallback_k(const float* __restrict__ A, const int* __restrict__ assign,
                           const float* __restrict__ W, float* __restrict__ out) {
    long idx = (long)blockIdx.x * 256 + threadIdx.x;  // NTOK*NOUT
    int t = (int)(idx >> 11);
    int n = (int)(idx & (NOUT - 1));
    int e = assign[t];
    const float4* a = (const float4*)(A + (size_t)t * KIN);
    const float4* w = (const float4*)(W + ((size_t)e * NOUT + n) * KIN);
    float s = 0.f;
    for (int k = 0; k < KIN / 4; k++) {
        float4 x = a[k], y = w[k];
        s += x.x * y.x + x.y * y.y + x.z * y.z + x.w * y.w;
    }
    out[idx] = s;
}

extern "C" void kernel_launch(void* const* d_in, const int* in_sizes, int n_in,
                              void* d_out, int out_size, void* d_ws, size_t ws_size,
                              hipStream_t stream) {
    const float* A = (const float*)d_in[0];
    const int* assign = (const int*)d_in[1];
    const float* W = (const float*)d_in[2];
    float* out = (float*)d_out;

    const size_t Ab_bytes = (size_t)NTOK * KIN * 2;            // 134 MB bf16 A
    const size_t Wb_bytes = (size_t)NEXP * NOUT * KIN * 2;     // 67 MB bf16 W
    const size_t list_bytes = (size_t)NTOK * 4;
    const size_t rank_bytes = (size_t)NTOK * 4;
    const size_t bb_bytes = (size_t)NBLK * NEXP * 4;
    const size_t ctrl_bytes = 256;
    const size_t tt_bytes = (size_t)MAXTILE * 16;
    const size_t need = Ab_bytes + Wb_bytes + list_bytes + rank_bytes +
                        bb_bytes + ctrl_bytes + tt_bytes;

    if (ws_size < need) {
        fallback_k<<<(NTOK * (long)NOUT) / 256, 256, 0, stream>>>(A, assign, W, out);
        return;
    }

    char* p = (char*)d_ws;
    u16* Ab = (u16*)p;                     p += Ab_bytes;
    u16* Wb = (u16*)p;                     p += Wb_bytes;
    int* list = (int*)p;                   p += list_bytes;
    int* rank = (int*)p;                   p += rank_bytes;
    int* blockBase = (int*)p;              p += bb_bytes;
    int* ctrl = (int*)p;                   p += ctrl_bytes;
    int4* tileTable = (int4*)p;

    hipMemsetAsync(ctrl, 0, ctrl_bytes, stream);
    rank_k<<<NBLK, 256, 0, stream>>>(assign, ctrl, rank, blockBase);
    prefix_k<<<1, 64, 0, stream>>>(ctrl, tileTable);
    scatter_k<<<NBLK, 256, 0, stream>>>(assign, ctrl, rank, blockBase, list);
    conv_k<<<(NTOK * (KIN / 8)) / 256, 256, 0, stream>>>(A, Ab);
    conv_k<<<(NEXP * NOUT * (KIN / 8)) / 256, 256, 0, stream>>>(W, Wb);
    dim3 grid(NOUT / BN, MAXTILE);
    gemm_k<<<grid, 256, 0, stream>>>(Ab, Wb, list, tileTable, out);
}